// Round 8
// baseline (331.899 us; speedup 1.0000x reference)
//
#include <hip/hip_runtime.h>
#include <hip/hip_bf16.h>
#include <stdint.h>

typedef unsigned int uint32;
typedef unsigned short ushort16;

typedef __attribute__((ext_vector_type(8))) short short8;
typedef __attribute__((ext_vector_type(4))) float f32x4;

#define N_NODES 50000
#define N_EDGES 800000
#define FD      128
#define NGRAPH  64
#define MTILES  3125   // N_NODES / 16 exactly
#define NBK     196    // coarse buckets = ceil(50000/256)
#define GB      391    // sort blocks (2048 edges each)
#define GB2     782    // fused gemm blocks (4 m-tiles each)
#define PCH     32     // pool chunks per graph
#define KCH     98     // scan_hist k-chunk = ceil(391/4)

__device__ __forceinline__ float bf2f(ushort16 u){
  union { uint32 i; float f; } v; v.i = ((uint32)u) << 16; return v.f;
}
__device__ __forceinline__ float bf2f_lo(uint32 w){ union{uint32 i;float f;}v; v.i = w << 16; return v.f; }
__device__ __forceinline__ float bf2f_hi(uint32 w){ union{uint32 i;float f;}v; v.i = w & 0xffff0000u; return v.f; }
__device__ __forceinline__ ushort16 f2bf(float f){
  uint32 u = __float_as_uint(f);
  u += 0x7fffu + ((u >> 16) & 1u);   // round-to-nearest-even
  return (ushort16)(u >> 16);
}

// flags[0] = 1 iff float inputs are f32 (else bf16); flags[1] = 1 iff indices are int64
__device__ __forceinline__ int ld_idx(const void* p, uint32 is64, size_t i){
  return is64 ? (int)((const long long*)p)[i] : ((const int*)p)[i];
}
__device__ __forceinline__ float ld_f(const void* p, uint32 isf32, int i){
  return isf32 ? ((const float*)p)[i] : bf2f(((const ushort16*)p)[i]);
}

// ---------------- dtype detection (device-side, 1 wave) ----------------

__global__ void detect_kernel(const uint32* __restrict__ xw, const uint32* __restrict__ eiw,
                              uint32* __restrict__ flags)
{
  int t = threadIdx.x;                       // 64 lanes
  uint32 w = xw[t];
  uint32 e8 = (w >> 7) & 0xFFu;              // exponent field of the LOW bf16 half
  bool bf_like = (e8 >= 0x70u && e8 <= 0x82u);
  unsigned long long m = __ballot(bf_like);
  uint32 hi = (t < 8) ? eiw[2*t + 1] : 1u;
  unsigned long long z = __ballot(hi == 0u);
  if (t == 0){
    flags[0] = (__popcll(m) < 32) ? 1u : 0u;          // isf32
    flags[1] = ((z & 0xFFull) == 0xFFull) ? 1u : 0u;  // is64
  }
}

// ---------------- CSR build: atomic-free 2-level bucket sort ----------------
// blocks [0,GB): pack edges + per-block LDS hist.  blocks [GB, GB+196): gseg.

__global__ __launch_bounds__(256) void pack_gseg_kernel(const void* __restrict__ ei,
    const void* __restrict__ batch, const uint32* __restrict__ flags,
    uint32* __restrict__ pack0, uint32* __restrict__ hist, uint32* __restrict__ gstart)
{
  uint32 is64 = flags[1];
  int tid = threadIdx.x;
  if (blockIdx.x < GB){
    __shared__ uint32 h[256];
    h[tid] = 0u;
    __syncthreads();
    int base = blockIdx.x*2048;
    for (int r = 0; r < 8; ++r){
      int i = base + r*256 + tid;
      if (i < N_EDGES){
        uint32 s = (uint32)ld_idx(ei, is64, i);
        uint32 d = (uint32)ld_idx(ei, is64, (size_t)N_EDGES + i);
        pack0[i] = (d << 16) | s;
        atomicAdd(&h[d >> 8], 1u);             // LDS atomic
      }
    }
    __syncthreads();
    hist[blockIdx.x*256 + tid] = h[tid];
  } else {
    int t = (blockIdx.x - GB)*256 + tid;
    if (t >= N_NODES) return;
    int b1 = ld_idx(batch, is64, t);
    int b0 = (t == 0) ? -1 : ld_idx(batch, is64, t - 1);
    for (int g = b0 + 1; g <= b1; ++g) gstart[g] = (uint32)t;
    if (t == N_NODES - 1)
      for (int g = b1 + 1; g <= NGRAPH; ++g) gstart[g] = (uint32)N_NODES;
  }
}

// 1024 threads: seg=tid>>8 handles k in [seg*KCH, ...): 98 serial iters not 391.
__global__ __launch_bounds__(1024) void scan_hist_kernel(const uint32* __restrict__ hist,
    uint32* __restrict__ off, uint32* __restrict__ bbase)
{
  __shared__ uint32 part[4][256];
  __shared__ uint32 lds[256];
  __shared__ uint32 bb[256];
  int tid = threadIdx.x;
  int seg = tid >> 8, b = tid & 255;
  int k0 = seg*KCH, k1 = (k0 + KCH < GB) ? k0 + KCH : GB;
  uint32 sum = 0;
  for (int k = k0; k < k1; ++k) sum += hist[k*256 + b];
  part[seg][b] = sum;
  __syncthreads();
  uint32 tot = 0, x = 0;
  if (seg == 0){
    tot = part[0][b] + part[1][b] + part[2][b] + part[3][b];
    x = tot; lds[b] = x;
  }
  __syncthreads();
  for (int o = 1; o < 256; o <<= 1){
    uint32 y = 0;
    if (seg == 0 && b >= o) y = lds[b - o];
    __syncthreads();
    if (seg == 0){ x += y; lds[b] = x; }
    __syncthreads();
  }
  if (seg == 0){
    uint32 base = x - tot;                     // exclusive bucket base
    bb[b] = base;
    if (b <= NBK) bbase[b] = (b < NBK) ? base : (uint32)N_EDGES;
  }
  __syncthreads();
  uint32 run = bb[b];
  for (int s = 0; s < seg; ++s) run += part[s][b];
  for (int k = k0; k < k1; ++k){
    off[k*256 + b] = run;
    run += hist[k*256 + b];
  }
}

__global__ __launch_bounds__(256) void scatter_kernel(const uint32* __restrict__ pack0,
    const uint32* __restrict__ off, uint32* __restrict__ pack1)
{
  __shared__ uint32 cur[256];
  int tid = threadIdx.x;
  cur[tid] = off[blockIdx.x*256 + tid];
  __syncthreads();
  int base = blockIdx.x*2048;
  for (int r = 0; r < 8; ++r){
    int i = base + r*256 + tid;
    if (i < N_EDGES){
      uint32 p = pack0[i];
      uint32 pos = atomicAdd(&cur[p >> 24], 1u);   // LDS atomic
      pack1[pos] = p;
    }
  }
}

__global__ __launch_bounds__(256) void bucket_csr_kernel(const uint32* __restrict__ pack1,
    const uint32* __restrict__ bbase, uint32* __restrict__ rowstart,
    uint32* __restrict__ deg, ushort16* __restrict__ colidx)
{
  __shared__ uint32 cnt[256];
  __shared__ uint32 lds[256];
  __shared__ uint32 cur[256];
  int tid = threadIdx.x;
  int bk = blockIdx.x;
  uint32 e0 = bbase[bk], e1 = bbase[bk + 1];
  cnt[tid] = 0u;
  __syncthreads();
  for (uint32 i = e0 + tid; i < e1; i += 256)
    atomicAdd(&cnt[(pack1[i] >> 16) & 255u], 1u);  // LDS atomic
  __syncthreads();
  uint32 v = cnt[tid];
  uint32 x = v;
  lds[tid] = x; __syncthreads();
  for (int o = 1; o < 256; o <<= 1){
    uint32 y = (tid >= o) ? lds[tid - o] : 0u;
    __syncthreads();
    x += y; lds[tid] = x;
    __syncthreads();
  }
  uint32 start = e0 + x - v;
  int node = bk*256 + tid;
  if (node < N_NODES){ rowstart[node] = start; deg[node] = v; }
  cur[tid] = start;
  __syncthreads();
  for (uint32 i = e0 + tid; i < e1; i += 256){
    uint32 p = pack1[i];
    uint32 pos = atomicAdd(&cur[(p >> 16) & 255u], 1u);  // LDS atomic
    colidx[pos] = (ushort16)(p & 0xFFFFu);
  }
}

// ---------------- prep: x->bf16 (f32 only) + W fragment layout --------------

__global__ __launch_bounds__(256) void prep_kernel(const void* __restrict__ X,
    const void* __restrict__ WL1, const void* __restrict__ WR1,
    const void* __restrict__ WL2, const void* __restrict__ WR2,
    const uint32* __restrict__ flags, ushort16* __restrict__ xb, short* __restrict__ wfrag)
{
  uint32 isf32 = flags[0];
  if (blockIdx.x < 3125){
    if (!isf32) return;                        // bf16 input used in place
    size_t e = ((size_t)blockIdx.x*256 + threadIdx.x)*8;
    const float* p = (const float*)X + e;
    float4 u = *(const float4*)p;
    float4 v = *(const float4*)(p + 4);
    uint4 o;
    o.x = (uint32)f2bf(u.x) | ((uint32)f2bf(u.y) << 16);
    o.y = (uint32)f2bf(u.z) | ((uint32)f2bf(u.w) << 16);
    o.z = (uint32)f2bf(v.x) | ((uint32)f2bf(v.y) << 16);
    o.w = (uint32)f2bf(v.z) | ((uint32)f2bf(v.w) << 16);
    *(uint4*)(xb + e) = o;
  } else {
    int t = (blockIdx.x - 3125)*256 + threadIdx.x;   // 65536 total
    int layer = t >> 15;
    int r = t & 32767;
    int k = r >> 7, n = r & 127;
    const void* w = layer ? (k < 128 ? WL2 : WR2) : (k < 128 ? WL1 : WR1);
    int kk = k & 127;
    float wv = ld_f(w, isf32, kk*128 + n);
    int off = (((k >> 5)*8 + (n >> 4))*64 + (n & 15) + 16*((kk >> 3) & 3))*8 + (kk & 7);
    wfrag[layer*32768 + off] = (short)f2bf(wv);
  }
}

// ---------------- fused aggregation + GEMM + bias + BN partials -------------
// One wave per 16-node m-tile; lane (lq,lm): node = mt*16+lm, gathers its
// node's neighbors' 4 x 16B slices (feats ks*32+lq*8..+8) into f32 mean
// accumulators -> A0 fragment in registers. A1 = self row direct loads.
// B from wfrag (global, L2-hot, fragment layout). No aggb materialization.

__device__ __forceinline__ void acc8u(float* a, uint4 v){
  a[0] += bf2f_lo(v.x); a[1] += bf2f_hi(v.x);
  a[2] += bf2f_lo(v.y); a[3] += bf2f_hi(v.y);
  a[4] += bf2f_lo(v.z); a[5] += bf2f_hi(v.z);
  a[6] += bf2f_lo(v.w); a[7] += bf2f_hi(v.w);
}

__global__ __launch_bounds__(256) void fused_gemm_kernel(
    const ushort16* __restrict__ Xd, const void* __restrict__ Xraw,
    const uint32* __restrict__ rowstart, const uint32* __restrict__ deg,
    const ushort16* __restrict__ colidx,
    const short* __restrict__ wfrag, const void* __restrict__ bias,
    const uint32* __restrict__ flags,
    ushort16* __restrict__ hpre, float* __restrict__ bnpart)
{
  __shared__ float red[256];
  uint32 isf32 = flags[0];
  const ushort16* X = (Xraw && !isf32) ? (const ushort16*)Xraw : Xd;
  int tid = threadIdx.x;
  red[tid] = 0.f;
  int wave = tid >> 6, lane = tid & 63, lq = lane >> 4, lm = lane & 15;
  int mt = blockIdx.x*4 + wave;
  bool valid = mt < MTILES;
  int node = (valid ? mt : 0)*16 + lm;
  uint32 st = rowstart[node];
  uint32 d = valid ? deg[node] : 0u;

  float ga[32];
#pragma unroll
  for (int i = 0; i < 32; ++i) ga[i] = 0.f;
  const ushort16* Xl = X + lq*8;
  uint32 j = 0;
  for (; j + 2 <= d; j += 2){                  // 2 neighbors x 4 slices in flight
    uint32 c0 = colidx[st + j];
    uint32 c1 = colidx[st + j + 1];
    const ushort16* p0 = Xl + (size_t)c0*FD;
    const ushort16* p1 = Xl + (size_t)c1*FD;
    uint4 v00 = *(const uint4*)(p0);
    uint4 v01 = *(const uint4*)(p0 + 32);
    uint4 v02 = *(const uint4*)(p0 + 64);
    uint4 v03 = *(const uint4*)(p0 + 96);
    uint4 v10 = *(const uint4*)(p1);
    uint4 v11 = *(const uint4*)(p1 + 32);
    uint4 v12 = *(const uint4*)(p1 + 64);
    uint4 v13 = *(const uint4*)(p1 + 96);
    acc8u(&ga[0],  v00); acc8u(&ga[8],  v01); acc8u(&ga[16], v02); acc8u(&ga[24], v03);
    acc8u(&ga[0],  v10); acc8u(&ga[8],  v11); acc8u(&ga[16], v12); acc8u(&ga[24], v13);
  }
  if (j < d){
    uint32 c0 = colidx[st + j];
    const ushort16* p0 = Xl + (size_t)c0*FD;
    uint4 v00 = *(const uint4*)(p0);
    uint4 v01 = *(const uint4*)(p0 + 32);
    uint4 v02 = *(const uint4*)(p0 + 64);
    uint4 v03 = *(const uint4*)(p0 + 96);
    acc8u(&ga[0],  v00); acc8u(&ga[8],  v01); acc8u(&ga[16], v02); acc8u(&ga[24], v03);
  }
  float inv = 1.f / fmaxf((float)d, 1.f);
  short8 af[4];
#pragma unroll
  for (int ks = 0; ks < 4; ++ks)
#pragma unroll
    for (int i = 0; i < 8; ++i)
      af[ks][i] = (short)f2bf(ga[ks*8 + i]*inv);

  f32x4 acc[8];
#pragma unroll
  for (int i = 0; i < 8; ++i) acc[i] = (f32x4){0.f,0.f,0.f,0.f};
  const short* selfp = (const short*)(X + (size_t)node*FD) + lq*8;
#pragma unroll
  for (int ks = 0; ks < 8; ++ks){
    short8 a = (ks < 4) ? af[ks] : *(const short8*)(selfp + (ks - 4)*32);
#pragma unroll
    for (int nt = 0; nt < 8; ++nt){
      short8 b = *(const short8*)&wfrag[((ks*8 + nt)*64 + lane)*8];
      acc[nt] = __builtin_amdgcn_mfma_f32_16x16x32_bf16(a, b, acc[nt], 0, 0, 0);
    }
  }

  __syncthreads();                             // red[] zero-init visible
#pragma unroll
  for (int nt = 0; nt < 8; ++nt){
    int colc = nt*16 + lm;                     // C/D: col = lane&15
    float bb = ld_f(bias, isf32, colc);
    float s = 0.f, s2 = 0.f;
    if (valid){
      size_t nb = (size_t)mt*16 + lq*4;        // C/D: row = quad*4 + reg
#pragma unroll
      for (int r = 0; r < 4; ++r){
        float val = acc[nt][r] + bb;
        hpre[(nb + r)*FD + colc] = f2bf(val);
        s += val; s2 += val*val;
      }
    }
    s  += __shfl_xor(s, 16);  s  += __shfl_xor(s, 32);
    s2 += __shfl_xor(s2, 16); s2 += __shfl_xor(s2, 32);
    if (lq == 0){
      atomicAdd(&red[colc], s);                // LDS atomic
      atomicAdd(&red[128 + colc], s2);
    }
  }
  __syncthreads();
  bnpart[blockIdx.x*256 + tid] = red[tid];
}

// ---------------- BN finalize (16 blocks, shfl reduce) ----------------------

__global__ __launch_bounds__(256) void bn_final_kernel(const float* __restrict__ bnpart,
    const void* __restrict__ gamma, const void* __restrict__ beta,
    const uint32* __restrict__ flags, float* __restrict__ scale, float* __restrict__ shift)
{
  uint32 isf32 = flags[0];
  int tid = threadIdx.x;
  int f = blockIdx.x*8 + (tid >> 5);
  int l = tid & 31;
  float s = 0.f, q = 0.f;
  for (int b = l; b < GB2; b += 32){
    s += bnpart[b*256 + f];
    q += bnpart[b*256 + 128 + f];
  }
#pragma unroll
  for (int m = 16; m >= 1; m >>= 1){
    s += __shfl_xor(s, m);
    q += __shfl_xor(q, m);
  }
  if (l == 0){
    const float invN = 1.0f / (float)N_NODES;
    float mu  = s * invN;
    float var = q * invN - mu*mu;
    float scv = ld_f(gamma, isf32, f) * rsqrtf(var + 1e-5f);
    scale[f] = scv;
    shift[f] = ld_f(beta, isf32, f) - mu * scv;
  }
}

// ---------------- BN1+ReLU apply: z1 = relu(affine(hp1)), bf16 --------------

__global__ __launch_bounds__(256) void bn_apply_kernel(const ushort16* __restrict__ hp,
    const float* __restrict__ scale, const float* __restrict__ shift, ushort16* __restrict__ z)
{
  size_t e = ((size_t)blockIdx.x*256 + threadIdx.x)*8;
  int c = (int)(e & 127);
  uint4 v = *(const uint4*)(hp + e);
  float f[8];
  f[0] = bf2f_lo(v.x); f[1] = bf2f_hi(v.x);
  f[2] = bf2f_lo(v.y); f[3] = bf2f_hi(v.y);
  f[4] = bf2f_lo(v.z); f[5] = bf2f_hi(v.z);
  f[6] = bf2f_lo(v.w); f[7] = bf2f_hi(v.w);
  ushort16 r[8];
#pragma unroll
  for (int j = 0; j < 8; ++j)
    r[j] = f2bf(fmaxf(f[j]*scale[c + j] + shift[c + j], 0.f));
  uint4 o;
  o.x = (uint32)r[0] | ((uint32)r[1] << 16);
  o.y = (uint32)r[2] | ((uint32)r[3] << 16);
  o.z = (uint32)r[4] | ((uint32)r[5] << 16);
  o.w = (uint32)r[6] | ((uint32)r[7] << 16);
  *(uint4*)(z + e) = o;
}

// ---------------- pool (BN2 + ReLU fused), high-occupancy -------------------

__global__ __launch_bounds__(256) void pool_partial_kernel(const ushort16* __restrict__ hp,
    const float* __restrict__ scale, const float* __restrict__ shift,
    const uint32* __restrict__ gstart, float* __restrict__ pool_part)
{
  __shared__ float wred[4*16*8];                 // 2 KB
  int tid = threadIdx.x;
  int g = blockIdx.x >> 5, chunk = blockIdx.x & 31;
  int slot = tid >> 4, l = tid & 15;
  int wave = tid >> 6, lane = tid & 63;
  uint32 st = gstart[g], cnt = gstart[g+1] - st;
  uint32 per = (cnt + PCH - 1) >> 5;
  uint32 b0 = st + chunk*per;
  uint32 b1 = b0 + per;
  uint32 e1 = st + cnt;
  if (b1 > e1) b1 = e1;
  float s0[8], h0[8], a[8];
#pragma unroll
  for (int j = 0; j < 8; ++j){ s0[j] = scale[l*8 + j]; h0[j] = shift[l*8 + j]; a[j] = 0.f; }
  for (uint32 n = b0 + slot; n < b1; n += 16){
    const uint4 v = *(const uint4*)(hp + (size_t)n*FD + l*8);
    float f[8];
    f[0] = bf2f_lo(v.x); f[1] = bf2f_hi(v.x);
    f[2] = bf2f_lo(v.y); f[3] = bf2f_hi(v.y);
    f[4] = bf2f_lo(v.z); f[5] = bf2f_hi(v.z);
    f[6] = bf2f_lo(v.w); f[7] = bf2f_hi(v.w);
#pragma unroll
    for (int j = 0; j < 8; ++j) a[j] += fmaxf(f[j]*s0[j] + h0[j], 0.f);
  }
#pragma unroll
  for (int j = 0; j < 8; ++j){
    a[j] += __shfl_xor(a[j], 16);
    a[j] += __shfl_xor(a[j], 32);
  }
  if (lane < 16){
#pragma unroll
    for (int j = 0; j < 8; ++j) wred[(wave*16 + lane)*8 + j] = a[j];
  }
  __syncthreads();
  if (tid < 16){
    float r[8];
#pragma unroll
    for (int j = 0; j < 8; ++j)
      r[j] = wred[(0*16 + tid)*8 + j] + wred[(1*16 + tid)*8 + j]
           + wred[(2*16 + tid)*8 + j] + wred[(3*16 + tid)*8 + j];
    float* dst = pool_part + (size_t)blockIdx.x*FD + tid*8;
#pragma unroll
    for (int j = 0; j < 8; ++j) dst[j] = r[j];
  }
}

__global__ void pool_final_kernel(const float* __restrict__ pool_part,
    const uint32* __restrict__ gstart, void* __restrict__ out, const uint32* __restrict__ flags)
{
  uint32 isf32 = flags[0];
  int t = blockIdx.x*256 + threadIdx.x;          // t < 8192
  int g = t >> 7, f = t & 127;
  float c = fmaxf((float)(gstart[g+1] - gstart[g]), 1.f);
  float v = 0.f;
#pragma unroll 8
  for (int ch = 0; ch < PCH; ++ch)
    v += pool_part[(size_t)(g*PCH + ch)*FD + f];
  v /= c;
  if (isf32) ((float*)out)[t] = v;
  else       ((ushort16*)out)[t] = f2bf(v);
}

// ---------------- launch ----------------

extern "C" void kernel_launch(void* const* d_in, const int* in_sizes, int n_in,
                              void* d_out, int out_size, void* d_ws, size_t ws_size,
                              hipStream_t stream)
{
  const void* x   = d_in[0];
  const void* ei  = d_in[1];
  const void* bat = d_in[2];
  const void* wl1 = d_in[3];
  const void* bl1 = d_in[4];
  const void* wr1 = d_in[5];
  const void* g1  = d_in[6];
  const void* be1 = d_in[7];
  const void* wl2 = d_in[8];
  const void* bl2 = d_in[9];
  const void* wr2 = d_in[10];
  const void* g2  = d_in[11];
  const void* be2 = d_in[12];
  char* ws = (char*)d_ws;

  // persistent
  uint32* flags   = (uint32*)(ws + 0);            // 2 u32
  uint32* gstart  = (uint32*)(ws + 64);           // 65 u32
  uint32* bbase   = (uint32*)(ws + 384);          // 197 u32 -> 1,172
  float*  bnpart  = (float*) (ws + 1280);         // 782*256 f32 -> 802,048
  float*  scale1  = (float*) (ws + 802048);
  float*  shift1  = (float*) (ws + 802560);
  float*  scale2  = (float*) (ws + 803072);
  float*  shift2  = (float*) (ws + 803584);
  uint32* rowstart= (uint32*)(ws + 804096);       // -> 1,004,096
  uint32* deg     = (uint32*)(ws + 1004096);      // -> 1,204,096
  ushort16* colidx= (ushort16*)(ws + 1204096);    // u16 -> 2,804,096
  short*  wfrag   = (short*) (ws + 2804096);      // 2 x 32768 shorts -> 2,935,168
  ushort16* xb    = (ushort16*)(ws + 2935168);    // 12.8 MB -> 15,735,168
  ushort16* z1    = (ushort16*)(ws + 15735168);   // 12.8 MB -> 28,535,168
  ushort16* hp1   = (ushort16*)(ws + 28535168);   // 12.8 MB -> 41,335,168
  ushort16* hp2   = (ushort16*)(ws + 41335168);   // 12.8 MB -> 54,135,168
  // transient, inside hp1/hp2 (dead before gemm1 writes hp1):
  uint32* pack0   = (uint32*)(ws + 28535168);     // 3.2 MB
  uint32* pack1   = (uint32*)(ws + 31735168);     // 3.2 MB
  uint32* hist    = (uint32*)(ws + 34935168);     // 391*256 u32
  uint32* off     = (uint32*)(ws + 35335552);     // 391*256 u32 -> 35,735,936
  // ppart overlaps pack0 (both dead when the other is live):
  float*  ppart   = (float*) (ws + 28535168);     // 2048*128 f32 (used only after hp1 dead)

  detect_kernel    <<<1,   64,  0, stream>>>((const uint32*)x, (const uint32*)ei, flags);

  // CSR build (no global atomics) + graph segments
  pack_gseg_kernel <<<GB + 196, 256, 0, stream>>>(ei, bat, flags, pack0, hist, gstart);
  scan_hist_kernel <<<1,  1024, 0, stream>>>(hist, off, bbase);
  scatter_kernel   <<<GB,  256, 0, stream>>>(pack0, off, pack1);
  bucket_csr_kernel<<<NBK, 256, 0, stream>>>(pack1, bbase, rowstart, deg, colidx);

  // prep (xcvt no-ops when input is bf16; wprep always)
  prep_kernel      <<<3381, 256, 0, stream>>>(x, wl1, wr1, wl2, wr2, flags, xb, wfrag);

  // layer 1 (fused agg+gemm; reads x directly when bf16)
  fused_gemm_kernel<<<GB2, 256, 0, stream>>>(xb, x, rowstart, deg, colidx,
                                             wfrag, bl1, flags, hp1, bnpart);
  bn_final_kernel  <<<16,  256, 0, stream>>>(bnpart, g1, be1, flags, scale1, shift1);
  bn_apply_kernel  <<<3125,256, 0, stream>>>(hp1, scale1, shift1, z1);

  // layer 2 (fused agg+gemm on z1)
  fused_gemm_kernel<<<GB2, 256, 0, stream>>>(z1, nullptr, rowstart, deg, colidx,
                                             wfrag + 32768, bl2, flags, hp2, bnpart);
  bn_final_kernel  <<<16,  256, 0, stream>>>(bnpart, g2, be2, flags, scale2, shift2);

  // pool (BN2 + ReLU fused; hp1 dead -> ppart may overlap its region)
  pool_partial_kernel<<<NGRAPH*PCH, 256, 0, stream>>>(hp2, scale2, shift2, gstart, ppart);
  pool_final_kernel  <<<32,  256, 0, stream>>>(ppart, gstart, d_out, flags);
}

// Round 9
// 287.102 us; speedup vs baseline: 1.1560x; 1.1560x over previous
//
#include <hip/hip_runtime.h>
#include <hip/hip_bf16.h>
#include <stdint.h>

typedef unsigned int uint32;
typedef unsigned short ushort16;

typedef __attribute__((ext_vector_type(8))) short short8;
typedef __attribute__((ext_vector_type(4))) float f32x4;

#define N_NODES 50000
#define N_EDGES 800000
#define FD      128
#define NGRAPH  64
#define MTILES  3125   // N_NODES / 16 exactly
#define NBK     196    // coarse buckets = ceil(50000/256)
#define GB      391    // sort blocks (2048 edges each)
#define GB2     782    // gemm blocks (4 m-tiles each, 1 per wave)
#define PCH     32     // pool chunks per graph
#define KCH     98     // scan_hist k-chunk = ceil(391/4)

__device__ __forceinline__ float bf2f(ushort16 u){
  union { uint32 i; float f; } v; v.i = ((uint32)u) << 16; return v.f;
}
__device__ __forceinline__ float bf2f_lo(uint32 w){ union{uint32 i;float f;}v; v.i = w << 16; return v.f; }
__device__ __forceinline__ float bf2f_hi(uint32 w){ union{uint32 i;float f;}v; v.i = w & 0xffff0000u; return v.f; }
__device__ __forceinline__ ushort16 f2bf(float f){
  uint32 u = __float_as_uint(f);
  u += 0x7fffu + ((u >> 16) & 1u);   // round-to-nearest-even
  return (ushort16)(u >> 16);
}

__device__ __forceinline__ int ld_idx(const void* p, uint32 is64, size_t i){
  return is64 ? (int)((const long long*)p)[i] : ((const int*)p)[i];
}
__device__ __forceinline__ float ld_f(const void* p, uint32 isf32, int i){
  return isf32 ? ((const float*)p)[i] : bf2f(((const ushort16*)p)[i]);
}

// ---- inline dtype detection (per-wave, 2 broadcast loads + 2 ballots) ------
// isf32: 1 iff x is f32 (else bf16).  is64: 1 iff edge_index/batch are int64.
__device__ __forceinline__ void get_flags(const uint32* __restrict__ xw,
    const uint32* __restrict__ eiw, uint32& isf32, uint32& is64)
{
  int l = threadIdx.x & 63;
  uint32 w = xw[l];
  uint32 e8 = (w >> 7) & 0xFFu;              // exponent of the LOW bf16 half
  bool bf_like = (e8 >= 0x70u && e8 <= 0x82u);
  unsigned long long m = __ballot(bf_like);
  isf32 = (__popcll(m) < 32) ? 1u : 0u;
  uint32 hi = (l < 8) ? eiw[2*l + 1] : 1u;   // int64 high words are 0
  unsigned long long z = __ballot(hi == 0u);
  is64 = ((z & 0xFFull) == 0xFFull) ? 1u : 0u;
}

// ---------------- CSR build + gseg + prep, one grid -------------------------
// blocks [0,GB): pack+hist.  [GB,GB+196): gseg.  [GB+196,+3125): xcvt.
// [GB+3321,+256): wprep.

__global__ __launch_bounds__(256) void pack_gseg_prep_kernel(
    const void* __restrict__ ei, const void* __restrict__ batch,
    const void* __restrict__ X,
    const void* __restrict__ WL1, const void* __restrict__ WR1,
    const void* __restrict__ WL2, const void* __restrict__ WR2,
    uint32* __restrict__ pack0, uint32* __restrict__ hist, uint32* __restrict__ gstart,
    ushort16* __restrict__ xb, short* __restrict__ wfrag)
{
  uint32 isf32, is64;
  get_flags((const uint32*)X, (const uint32*)ei, isf32, is64);
  int tid = threadIdx.x;
  if (blockIdx.x < GB){
    __shared__ uint32 h[256];
    h[tid] = 0u;
    __syncthreads();
    int base = blockIdx.x*2048;
    for (int r = 0; r < 8; ++r){
      int i = base + r*256 + tid;
      if (i < N_EDGES){
        uint32 s = (uint32)ld_idx(ei, is64, i);
        uint32 d = (uint32)ld_idx(ei, is64, (size_t)N_EDGES + i);
        pack0[i] = (d << 16) | s;
        atomicAdd(&h[d >> 8], 1u);             // LDS atomic
      }
    }
    __syncthreads();
    hist[blockIdx.x*256 + tid] = h[tid];
  } else if (blockIdx.x < GB + 196){
    int t = (blockIdx.x - GB)*256 + tid;
    if (t >= N_NODES) return;
    int b1 = ld_idx(batch, is64, t);
    int b0 = (t == 0) ? -1 : ld_idx(batch, is64, t - 1);
    for (int g = b0 + 1; g <= b1; ++g) gstart[g] = (uint32)t;
    if (t == N_NODES - 1)
      for (int g = b1 + 1; g <= NGRAPH; ++g) gstart[g] = (uint32)N_NODES;
  } else if (blockIdx.x < GB + 196 + 3125){
    if (!isf32) return;                        // bf16 input used in place
    size_t e = ((size_t)(blockIdx.x - GB - 196)*256 + tid)*8;
    const float* p = (const float*)X + e;
    float4 u = *(const float4*)p;
    float4 v = *(const float4*)(p + 4);
    uint4 o;
    o.x = (uint32)f2bf(u.x) | ((uint32)f2bf(u.y) << 16);
    o.y = (uint32)f2bf(u.z) | ((uint32)f2bf(u.w) << 16);
    o.z = (uint32)f2bf(v.x) | ((uint32)f2bf(v.y) << 16);
    o.w = (uint32)f2bf(v.z) | ((uint32)f2bf(v.w) << 16);
    *(uint4*)(xb + e) = o;
  } else {
    int t = (blockIdx.x - GB - 196 - 3125)*256 + tid;   // 65536 total
    int layer = t >> 15;
    int r = t & 32767;
    int k = r >> 7, n = r & 127;
    const void* w = layer ? (k < 128 ? WL2 : WR2) : (k < 128 ? WL1 : WR1);
    int kk = k & 127;
    float wv = ld_f(w, isf32, kk*128 + n);
    int off = (((k >> 5)*8 + (n >> 4))*64 + (n & 15) + 16*((kk >> 3) & 3))*8 + (kk & 7);
    wfrag[layer*32768 + off] = (short)f2bf(wv);
  }
}

// 1024 threads: seg=tid>>8 handles k in [seg*KCH, ...): 98 serial iters.
__global__ __launch_bounds__(1024) void scan_hist_kernel(const uint32* __restrict__ hist,
    uint32* __restrict__ off, uint32* __restrict__ bbase)
{
  __shared__ uint32 part[4][256];
  __shared__ uint32 lds[256];
  __shared__ uint32 bb[256];
  int tid = threadIdx.x;
  int seg = tid >> 8, b = tid & 255;
  int k0 = seg*KCH, k1 = (k0 + KCH < GB) ? k0 + KCH : GB;
  uint32 sum = 0;
  for (int k = k0; k < k1; ++k) sum += hist[k*256 + b];
  part[seg][b] = sum;
  __syncthreads();
  uint32 tot = 0, x = 0;
  if (seg == 0){
    tot = part[0][b] + part[1][b] + part[2][b] + part[3][b];
    x = tot; lds[b] = x;
  }
  __syncthreads();
  for (int o = 1; o < 256; o <<= 1){
    uint32 y = 0;
    if (seg == 0 && b >= o) y = lds[b - o];
    __syncthreads();
    if (seg == 0){ x += y; lds[b] = x; }
    __syncthreads();
  }
  if (seg == 0){
    uint32 base = x - tot;
    bb[b] = base;
    if (b <= NBK) bbase[b] = (b < NBK) ? base : (uint32)N_EDGES;
  }
  __syncthreads();
  uint32 run = bb[b];
  for (int s = 0; s < seg; ++s) run += part[s][b];
  for (int k = k0; k < k1; ++k){
    off[k*256 + b] = run;
    run += hist[k*256 + b];
  }
}

__global__ __launch_bounds__(256) void scatter_kernel(const uint32* __restrict__ pack0,
    const uint32* __restrict__ off, uint32* __restrict__ pack1)
{
  __shared__ uint32 cur[256];
  int tid = threadIdx.x;
  cur[tid] = off[blockIdx.x*256 + tid];
  __syncthreads();
  int base = blockIdx.x*2048;
  for (int r = 0; r < 8; ++r){
    int i = base + r*256 + tid;
    if (i < N_EDGES){
      uint32 p = pack0[i];
      uint32 pos = atomicAdd(&cur[p >> 24], 1u);   // LDS atomic
      pack1[pos] = p;
    }
  }
}

__global__ __launch_bounds__(256) void bucket_csr_kernel(const uint32* __restrict__ pack1,
    const uint32* __restrict__ bbase, uint32* __restrict__ rowstart,
    uint32* __restrict__ deg, ushort16* __restrict__ colidx)
{
  __shared__ uint32 cnt[256];
  __shared__ uint32 lds[256];
  __shared__ uint32 cur[256];
  int tid = threadIdx.x;
  int bk = blockIdx.x;
  uint32 e0 = bbase[bk], e1 = bbase[bk + 1];
  cnt[tid] = 0u;
  __syncthreads();
  for (uint32 i = e0 + tid; i < e1; i += 256)
    atomicAdd(&cnt[(pack1[i] >> 16) & 255u], 1u);  // LDS atomic
  __syncthreads();
  uint32 v = cnt[tid];
  uint32 x = v;
  lds[tid] = x; __syncthreads();
  for (int o = 1; o < 256; o <<= 1){
    uint32 y = (tid >= o) ? lds[tid - o] : 0u;
    __syncthreads();
    x += y; lds[tid] = x;
    __syncthreads();
  }
  uint32 start = e0 + x - v;
  int node = bk*256 + tid;
  if (node < N_NODES){ rowstart[node] = start; deg[node] = v; }
  cur[tid] = start;
  __syncthreads();
  for (uint32 i = e0 + tid; i < e1; i += 256){
    uint32 p = pack1[i];
    uint32 pos = atomicAdd(&cur[(p >> 16) & 255u], 1u);  // LDS atomic
    colidx[pos] = (ushort16)(p & 0xFFFFu);
  }
}

// ---------------- mean aggregation (pull, CSR); APPLY fuses BN+ReLU --------
// 16 lanes per node (full coalescing, same-d lanes). Unroll-8 gathers in
// flight + vectorized colidx loads (uint2 = 4 indices).

__device__ __forceinline__ void acc8(float* a, uint4 v, const float* s0, const float* h0, int APPLY){
  float f[8];
  f[0] = bf2f_lo(v.x); f[1] = bf2f_hi(v.x);
  f[2] = bf2f_lo(v.y); f[3] = bf2f_hi(v.y);
  f[4] = bf2f_lo(v.z); f[5] = bf2f_hi(v.z);
  f[6] = bf2f_lo(v.w); f[7] = bf2f_hi(v.w);
#pragma unroll
  for (int j = 0; j < 8; ++j)
    a[j] += APPLY ? fmaxf(f[j]*s0[j] + h0[j], 0.f) : f[j];
}

template<int APPLY>
__global__ __launch_bounds__(256) void agg_kernel(const ushort16* __restrict__ Xd,
    const void* __restrict__ Xraw, const void* __restrict__ eiraw,
    const uint32* __restrict__ rowstart, const uint32* __restrict__ deg,
    const ushort16* __restrict__ colidx,
    const float* __restrict__ sc, const float* __restrict__ sh,
    ushort16* __restrict__ out)
{
  uint32 isf32, is64;
  get_flags((const uint32*)Xraw, (const uint32*)eiraw, isf32, is64);
  const ushort16* X = (APPLY == 0 && !isf32) ? (const ushort16*)Xraw : Xd;
  int t = blockIdx.x*256 + threadIdx.x;
  int node = t >> 4;
  int l = t & 15;
  uint32 st = rowstart[node];
  uint32 d  = deg[node];
  float s0[8], h0[8];
#pragma unroll
  for (int j = 0; j < 8; ++j){
    s0[j] = APPLY ? sc[l*8 + j] : 0.f;
    h0[j] = APPLY ? sh[l*8 + j] : 0.f;
  }
  float a[8];
#pragma unroll
  for (int j = 0; j < 8; ++j) a[j] = 0.f;
  const ushort16* Xl = X + l*8;
  uint32 i = 0;
  // align (st+i) to 4 for uint2 colidx loads
  for (; i < d && ((st + i) & 3u); ++i){
    uint32 c = colidx[st + i];
    acc8(a, *(const uint4*)(Xl + (size_t)c*FD), s0, h0, APPLY);
  }
  for (; i + 8 <= d; i += 8){
    uint2 cA = *(const uint2*)(colidx + st + i);
    uint2 cB = *(const uint2*)(colidx + st + i + 4);
    uint4 v0 = *(const uint4*)(Xl + (size_t)(cA.x & 0xFFFFu)*FD);
    uint4 v1 = *(const uint4*)(Xl + (size_t)(cA.x >> 16)*FD);
    uint4 v2 = *(const uint4*)(Xl + (size_t)(cA.y & 0xFFFFu)*FD);
    uint4 v3 = *(const uint4*)(Xl + (size_t)(cA.y >> 16)*FD);
    uint4 v4 = *(const uint4*)(Xl + (size_t)(cB.x & 0xFFFFu)*FD);
    uint4 v5 = *(const uint4*)(Xl + (size_t)(cB.x >> 16)*FD);
    uint4 v6 = *(const uint4*)(Xl + (size_t)(cB.y & 0xFFFFu)*FD);
    uint4 v7 = *(const uint4*)(Xl + (size_t)(cB.y >> 16)*FD);
    acc8(a, v0, s0, h0, APPLY); acc8(a, v1, s0, h0, APPLY);
    acc8(a, v2, s0, h0, APPLY); acc8(a, v3, s0, h0, APPLY);
    acc8(a, v4, s0, h0, APPLY); acc8(a, v5, s0, h0, APPLY);
    acc8(a, v6, s0, h0, APPLY); acc8(a, v7, s0, h0, APPLY);
  }
  for (; i + 4 <= d; i += 4){
    uint2 cA = *(const uint2*)(colidx + st + i);
    uint4 v0 = *(const uint4*)(Xl + (size_t)(cA.x & 0xFFFFu)*FD);
    uint4 v1 = *(const uint4*)(Xl + (size_t)(cA.x >> 16)*FD);
    uint4 v2 = *(const uint4*)(Xl + (size_t)(cA.y & 0xFFFFu)*FD);
    uint4 v3 = *(const uint4*)(Xl + (size_t)(cA.y >> 16)*FD);
    acc8(a, v0, s0, h0, APPLY); acc8(a, v1, s0, h0, APPLY);
    acc8(a, v2, s0, h0, APPLY); acc8(a, v3, s0, h0, APPLY);
  }
  for (; i < d; ++i){
    uint32 c = colidx[st + i];
    acc8(a, *(const uint4*)(Xl + (size_t)c*FD), s0, h0, APPLY);
  }
  float inv = 1.f / fmaxf((float)d, 1.f);
  uint4 o;
  o.x = (uint32)f2bf(a[0]*inv) | ((uint32)f2bf(a[1]*inv) << 16);
  o.y = (uint32)f2bf(a[2]*inv) | ((uint32)f2bf(a[3]*inv) << 16);
  o.z = (uint32)f2bf(a[4]*inv) | ((uint32)f2bf(a[5]*inv) << 16);
  o.w = (uint32)f2bf(a[6]*inv) | ((uint32)f2bf(a[7]*inv) << 16);
  *(uint4*)(out + (size_t)node*FD + l*8) = o;
}

// ---------------- GEMM + bias + BN-stat partials (1 m-tile per wave) --------

__device__ __forceinline__ short8 affine_relu8(short8 a, const float* sc, const float* sh, int koff){
  short8 r;
#pragma unroll
  for (int j = 0; j < 8; ++j){
    float v = bf2f((ushort16)a[j]) * sc[koff + j] + sh[koff + j];
    r[j] = (short)f2bf(fmaxf(v, 0.f));
  }
  return r;
}

template<int APPLY>
__global__ __launch_bounds__(256) void gemm_bn_kernel(
    const ushort16* __restrict__ A0, const ushort16* __restrict__ A1d,
    const void* __restrict__ A1raw, const void* __restrict__ eiraw,
    const short* __restrict__ wfrag, const void* __restrict__ bias,
    const float* __restrict__ sc, const float* __restrict__ sh,
    const void* __restrict__ Xraw,
    ushort16* __restrict__ hpre, float* __restrict__ bnpart)
{
  __shared__ float red[256];
  uint32 isf32, is64;
  get_flags((const uint32*)Xraw, (const uint32*)eiraw, isf32, is64);
  const ushort16* A1 = (A1raw && !isf32) ? (const ushort16*)A1raw : A1d;
  int tid = threadIdx.x;
  red[tid] = 0.f;
  int wave = tid >> 6, lane = tid & 63, lq = lane >> 4, lm = lane & 15;
  int mt = blockIdx.x*4 + wave;
  bool valid = mt < MTILES;
  size_t m0 = (size_t)((valid ? mt : 0)*16 + lm);
  f32x4 acc[8];
#pragma unroll
  for (int i = 0; i < 8; ++i) acc[i] = (f32x4){0.f,0.f,0.f,0.f};

#pragma unroll
  for (int ks = 0; ks < 8; ++ks){
    int koff = (ks & 3)*32 + lq*8;
    const short* srcp = (const short*)(ks < 4 ? A0 : A1);
    short8 a = *(const short8*)(srcp + m0*FD + koff);
    if (APPLY && ks >= 4) a = affine_relu8(a, sc, sh, koff);
#pragma unroll
    for (int nt = 0; nt < 8; ++nt){
      short8 b = *(const short8*)&wfrag[((ks*8 + nt)*64 + lane)*8];
      acc[nt] = __builtin_amdgcn_mfma_f32_16x16x32_bf16(a, b, acc[nt], 0, 0, 0);
    }
  }

  __syncthreads();                              // red[] zero-init visible
#pragma unroll
  for (int nt = 0; nt < 8; ++nt){
    int colc = nt*16 + lm;                      // C/D: col = lane&15
    float bb = ld_f(bias, isf32, colc);
    float s = 0.f, s2 = 0.f;
    if (valid){
      size_t nb = (size_t)mt*16 + lq*4;         // C/D: row = quad*4 + reg
#pragma unroll
      for (int r = 0; r < 4; ++r){
        float val = acc[nt][r] + bb;
        hpre[(nb + r)*FD + colc] = f2bf(val);
        s += val; s2 += val*val;
      }
    }
    s  += __shfl_xor(s, 16);  s  += __shfl_xor(s, 32);
    s2 += __shfl_xor(s2, 16); s2 += __shfl_xor(s2, 32);
    if (lq == 0){
      atomicAdd(&red[colc], s);                 // LDS atomic
      atomicAdd(&red[128 + colc], s2);
    }
  }
  __syncthreads();
  bnpart[blockIdx.x*256 + tid] = red[tid];
}

// ---------------- BN finalize (16 blocks, shfl reduce) ----------------------

__global__ __launch_bounds__(256) void bn_final_kernel(const float* __restrict__ bnpart,
    const void* __restrict__ gamma, const void* __restrict__ beta,
    const void* __restrict__ Xraw, const void* __restrict__ eiraw,
    float* __restrict__ scale, float* __restrict__ shift)
{
  uint32 isf32, is64;
  get_flags((const uint32*)Xraw, (const uint32*)eiraw, isf32, is64);
  int tid = threadIdx.x;
  int f = blockIdx.x*8 + (tid >> 5);
  int l = tid & 31;
  float s = 0.f, q = 0.f;
  for (int b = l; b < GB2; b += 32){
    s += bnpart[b*256 + f];
    q += bnpart[b*256 + 128 + f];
  }
#pragma unroll
  for (int m = 16; m >= 1; m >>= 1){
    s += __shfl_xor(s, m);
    q += __shfl_xor(q, m);
  }
  if (l == 0){
    const float invN = 1.0f / (float)N_NODES;
    float mu  = s * invN;
    float var = q * invN - mu*mu;
    float scv = ld_f(gamma, isf32, f) * rsqrtf(var + 1e-5f);
    scale[f] = scv;
    shift[f] = ld_f(beta, isf32, f) - mu * scv;
  }
}

// ---------------- pool (BN2 + ReLU fused), high-occupancy -------------------

__global__ __launch_bounds__(256) void pool_partial_kernel(const ushort16* __restrict__ hp,
    const float* __restrict__ scale, const float* __restrict__ shift,
    const uint32* __restrict__ gstart, float* __restrict__ pool_part)
{
  __shared__ float wred[4*16*8];                 // 2 KB
  int tid = threadIdx.x;
  int g = blockIdx.x >> 5, chunk = blockIdx.x & 31;
  int slot = tid >> 4, l = tid & 15;
  int wave = tid >> 6, lane = tid & 63;
  uint32 st = gstart[g], cnt = gstart[g+1] - st;
  uint32 per = (cnt + PCH - 1) >> 5;
  uint32 b0 = st + chunk*per;
  uint32 b1 = b0 + per;
  uint32 e1 = st + cnt;
  if (b1 > e1) b1 = e1;
  float s0[8], h0[8], a[8];
#pragma unroll
  for (int j = 0; j < 8; ++j){ s0[j] = scale[l*8 + j]; h0[j] = shift[l*8 + j]; a[j] = 0.f; }
  for (uint32 n = b0 + slot; n < b1; n += 16){
    const uint4 v = *(const uint4*)(hp + (size_t)n*FD + l*8);
    float f[8];
    f[0] = bf2f_lo(v.x); f[1] = bf2f_hi(v.x);
    f[2] = bf2f_lo(v.y); f[3] = bf2f_hi(v.y);
    f[4] = bf2f_lo(v.z); f[5] = bf2f_hi(v.z);
    f[6] = bf2f_lo(v.w); f[7] = bf2f_hi(v.w);
#pragma unroll
    for (int j = 0; j < 8; ++j) a[j] += fmaxf(f[j]*s0[j] + h0[j], 0.f);
  }
#pragma unroll
  for (int j = 0; j < 8; ++j){
    a[j] += __shfl_xor(a[j], 16);
    a[j] += __shfl_xor(a[j], 32);
  }
  if (lane < 16){
#pragma unroll
    for (int j = 0; j < 8; ++j) wred[(wave*16 + lane)*8 + j] = a[j];
  }
  __syncthreads();
  if (tid < 16){
    float r[8];
#pragma unroll
    for (int j = 0; j < 8; ++j)
      r[j] = wred[(0*16 + tid)*8 + j] + wred[(1*16 + tid)*8 + j]
           + wred[(2*16 + tid)*8 + j] + wred[(3*16 + tid)*8 + j];
    float* dst = pool_part + (size_t)blockIdx.x*FD + tid*8;
#pragma unroll
    for (int j = 0; j < 8; ++j) dst[j] = r[j];
  }
}

__global__ void pool_final_kernel(const float* __restrict__ pool_part,
    const uint32* __restrict__ gstart, const void* __restrict__ Xraw,
    const void* __restrict__ eiraw, void* __restrict__ out)
{
  uint32 isf32, is64;
  get_flags((const uint32*)Xraw, (const uint32*)eiraw, isf32, is64);
  int t = blockIdx.x*256 + threadIdx.x;          // t < 8192
  int g = t >> 7, f = t & 127;
  float c = fmaxf((float)(gstart[g+1] - gstart[g]), 1.f);
  float v = 0.f;
#pragma unroll 8
  for (int ch = 0; ch < PCH; ++ch)
    v += pool_part[(size_t)(g*PCH + ch)*FD + f];
  v /= c;
  if (isf32) ((float*)out)[t] = v;
  else       ((ushort16*)out)[t] = f2bf(v);
}

// ---------------- launch ----------------

extern "C" void kernel_launch(void* const* d_in, const int* in_sizes, int n_in,
                              void* d_out, int out_size, void* d_ws, size_t ws_size,
                              hipStream_t stream)
{
  const void* x   = d_in[0];
  const void* ei  = d_in[1];
  const void* bat = d_in[2];
  const void* wl1 = d_in[3];
  const void* bl1 = d_in[4];
  const void* wr1 = d_in[5];
  const void* g1  = d_in[6];
  const void* be1 = d_in[7];
  const void* wl2 = d_in[8];
  const void* bl2 = d_in[9];
  const void* wr2 = d_in[10];
  const void* g2  = d_in[11];
  const void* be2 = d_in[12];
  char* ws = (char*)d_ws;

  // persistent
  uint32* gstart  = (uint32*)(ws + 64);           // 65 u32
  uint32* bbase   = (uint32*)(ws + 384);          // 197 u32
  float*  bnpart  = (float*) (ws + 1280);         // 782*256 f32 -> 802,048
  float*  scale1  = (float*) (ws + 802048);
  float*  shift1  = (float*) (ws + 802560);
  float*  scale2  = (float*) (ws + 803072);
  float*  shift2  = (float*) (ws + 803584);
  uint32* rowstart= (uint32*)(ws + 804096);       // -> 1,004,096
  uint32* deg     = (uint32*)(ws + 1004096);      // -> 1,204,096
  ushort16* colidx= (ushort16*)(ws + 1204096);    // u16 -> 2,804,096
  short*  wfrag   = (short*) (ws + 2804096);      // 2 x 32768 shorts -> 2,935,168
  ushort16* xb    = (ushort16*)(ws + 2935168);    // 12.8 MB -> 15,735,168
  ushort16* aggb  = (ushort16*)(ws + 15735168);   // 12.8 MB -> 28,535,168
  ushort16* hp1   = (ushort16*)(ws + 28535168);   // 12.8 MB -> 41,335,168
  ushort16* hp2   = (ushort16*)(ws + 41335168);   // 12.8 MB -> 54,135,168
  // transient, inside hp1 (dead before gemm1 writes hp1):
  uint32* pack0   = (uint32*)(ws + 28535168);     // 3.2 MB
  uint32* pack1   = (uint32*)(ws + 31735168);     // 3.2 MB
  uint32* hist    = (uint32*)(ws + 34935168);     // 391*256 u32
  uint32* off     = (uint32*)(ws + 35335552);     // 391*256 u32
  // ppart overlaps pack0 region (pool runs after hp1's last read)
  float*  ppart   = (float*) (ws + 28535168);     // 2048*128 f32

  // CSR build + gseg + xcvt + wprep (one grid, no global atomics)
  pack_gseg_prep_kernel<<<GB + 196 + 3125 + 256, 256, 0, stream>>>(
      ei, bat, x, wl1, wr1, wl2, wr2, pack0, hist, gstart, xb, wfrag);
  scan_hist_kernel <<<1,  1024, 0, stream>>>(hist, off, bbase);
  scatter_kernel   <<<GB,  256, 0, stream>>>(pack0, off, pack1);
  bucket_csr_kernel<<<NBK, 256, 0, stream>>>(pack1, bbase, rowstart, deg, colidx);

  // layer 1 (reads x directly when bf16)
  agg_kernel<0>    <<<3125, 256, 0, stream>>>(xb, x, ei, rowstart, deg, colidx,
                                              nullptr, nullptr, aggb);
  gemm_bn_kernel<0><<<GB2,  256, 0, stream>>>(aggb, xb, x, ei, wfrag, bl1,
                                              nullptr, nullptr, x, hp1, bnpart);
  bn_final_kernel  <<<16,   256, 0, stream>>>(bnpart, g1, be1, x, ei, scale1, shift1);

  // layer 2 (BN1+ReLU fused into agg gather and gemm A1 operand)
  agg_kernel<1>    <<<3125, 256, 0, stream>>>(hp1, x, ei, rowstart, deg, colidx,
                                              scale1, shift1, aggb);
  gemm_bn_kernel<1><<<GB2,  256, 0, stream>>>(aggb, hp1, nullptr, ei, wfrag + 32768, bl2,
                                              scale1, shift1, x, hp2, bnpart);
  bn_final_kernel  <<<16,   256, 0, stream>>>(bnpart, g2, be2, x, ei, scale2, shift2);

  // pool (BN2 + ReLU fused)
  pool_partial_kernel<<<NGRAPH*PCH, 256, 0, stream>>>(hp2, scale2, shift2, gstart, ppart);
  pool_final_kernel  <<<32,  256, 0, stream>>>(ppart, gstart, x, ei, d_out);
}